// Round 3
// baseline (326.997 us; speedup 1.0000x reference)
//
#include <hip/hip_runtime.h>

// LoG: GaussianBlur(3x3, sigma=1, BORDER_REFLECT_101) -> Laplacian(ksize=9) -> +1 -> clip[0,255]
// x: [32,512,512,3] float32 NHWC. out: same.
//
// Full composition: blur kernel G3xG3, lap kernel = (C6xC6) *2D cross3 where
//   S9 = C6*[1,2,1], D9 = C6*[1,-2,1], cross3 = [[2,0,2],[0,-8,0],[2,0,2]].
// With U = G3*C6 (9-tap, sum 64): total = (U x U) *2D cross3.
// INTERIOR blocks (out rows & cols in [5,506]; no reflect fires in the reference):
//   S1': x (global, registers) -vert 9-tap U-> vU (LDS)
//   S2': vU -horz 9-tap U-> P (LDS)
//   S3': 5-point cross on P -> +1, clip, store          [2 barriers, no x staging]
// BOUNDARY blocks (row/col tile 0 or last): per-stage reflect-101 preserved:
//   B1: x -> blur tile (G^2 fused on the fly, double-reflected rows/cols)
//   B2: blur -C6 vert-> vq;  B3: vq -C6 horz-> P;  shared S3'.
// LDS peak 5112 floats = 20448 B -> 8 blocks/CU (was 24 KB -> 6).

#define TH 16
#define TW 32
#define HIMG 512
#define WIMG 512
#define ROWF (WIMG*3)    // 1536 floats per image row

#define VUW 132          // vU stride (floats); 128 written + 4 pad (odd quad stride)
#define PW  108          // P stride; 104 written (34 px + pad)
#define BLW 120          // boundary blur stride (40 px)
#define VQW 124          // boundary vq stride (30 quads written + 1 pad quad)

// LDS float layout (aliased by path/stage):
//   interior: vU [0,2376)                     P [2376,4320)
//   boundary: vq [0,2232)  blur [2232,5112)   P [2376,4320) (overlays dead blur)
#define OFF_P  2376
#define OFF_BL 2232
#define SM_TOTAL 5112    // 20448 B

__device__ __forceinline__ int reflect101(int i, int n) {
    i = (i < 0) ? -i : i;
    return (i >= n) ? (2 * n - 2 - i) : i;
}

__device__ __forceinline__ float4 fma4(float s, const float4& a, const float4& b) {
    return make_float4(fmaf(s, a.x, b.x), fmaf(s, a.y, b.y),
                       fmaf(s, a.z, b.z), fmaf(s, a.w, b.w));
}

__device__ __forceinline__ float c6dot(float f0, float f1, float f2, float f3,
                                       float f4, float f5, float f6) {
    return fmaf(20.f, f3, fmaf(6.f, f1 + f5, fmaf(15.f, f2 + f4, f0 + f6)));
}

__device__ __forceinline__ float4 c6dot4(const float4& a, const float4& b, const float4& c,
                                         const float4& d, const float4& e, const float4& f,
                                         const float4& g) {
    return make_float4(c6dot(a.x, b.x, c.x, d.x, e.x, f.x, g.x),
                       c6dot(a.y, b.y, c.y, d.y, e.y, f.y, g.y),
                       c6dot(a.z, b.z, c.z, d.z, e.z, f.z, g.z),
                       c6dot(a.w, b.w, c.w, d.w, e.w, f.w, g.w));
}

__device__ __forceinline__ float4 g3(const float4& a, const float4& b, const float4& c,
                                     float G0, float G1) {
    return make_float4(G0 * (a.x + c.x) + G1 * b.x,
                       G0 * (a.y + c.y) + G1 * b.y,
                       G0 * (a.z + c.z) + G1 * b.z,
                       G0 * (a.w + c.w) + G1 * b.w);
}

// U = G3 * C6: {U0,U1,U2,U3,U4,U3,U2,U1,U0}, sum = 64
#define U0 0.27406862f
#define U1 2.09627447f
#define U2 7.09627447f
#define U3 13.90372553f
#define U4 17.25931382f

__global__ __launch_bounds__(256, 8)
void log_fused(const float* __restrict__ x, float* __restrict__ out) {
    __shared__ __align__(16) float smem[SM_TOTAL];
    float* const vU   = smem;            // interior: 18 x 132
    float* const vq   = smem;            // boundary: 18 x 124
    float* const blur = smem + OFF_BL;   // boundary: 24 x 120
    float* const P    = smem + OFF_P;    // both:     18 x 108

    const int tid  = threadIdx.x;
    const int col0 = blockIdx.x * TW;
    const int row0 = blockIdx.y * TH;
    const int n    = blockIdx.z;
    const float* const xi = x + (size_t)n * HIMG * ROWF;

    const float G0 = 0.2740686190f, G1 = 0.4518627620f;

    const bool interior = (row0 != 0) && (row0 != HIMG - TH) &&
                          (col0 != 0) && (col0 != WIMG - TW);

    if (interior) {
        // ---- S1': vertical 9-tap U, x(global) -> vU, 2-row register block ----
        // vU row v (0..17) <-> image row row0-1+v; vU float f <-> x float 3*col0-16+f.
        // Thread (q, rp): quad q of rows 2rp, 2rp+1; reads x rows row0-5+2rp+j, j=0..9.
        const float Uk[10] = {U0, U1, U2, U3, U4, U3, U2, U1, U0, 0.f};
        for (int g = tid; g < 288; g += 256) {
            const int q  = g & 31;
            const int rp = g >> 5;              // 0..8
            const float* xp = xi + (size_t)(row0 - 5 + 2 * rp) * ROWF
                                 + (3 * col0 - 16 + 4 * q);
            float4 a0 = make_float4(0.f, 0.f, 0.f, 0.f), a1 = a0;
            #pragma unroll
            for (int j = 0; j < 10; ++j) {
                const float4 w = *(const float4*)(xp + (size_t)j * ROWF);
                if (j < 9) a0 = fma4(Uk[j], w, a0);
                if (j > 0) a1 = fma4(Uk[j - 1], w, a1);
            }
            float* vp = vU + (2 * rp) * VUW + 4 * q;
            *(float4*)vp         = a0;
            *(float4*)(vp + VUW) = a1;
        }
        __syncthreads();

        // ---- S2': horizontal 9-tap U (pixel stride = 3 floats), vU -> P ----
        // P float j <-> image float 3*col0-3+j; P[j] = sum_k U[k]*vU[j+1+3k].
        if (tid < 234) {                        // 18 rows x 13 groups of 8
            const int t = tid % 13;
            const int v = tid / 13;
            const float* vr = vU + v * VUW + 8 * t;
            float f[36];
            #pragma unroll
            for (int c = 0; c < 9; ++c) {
                const float4 w = *(const float4*)(vr + 4 * c);
                f[4*c+0] = w.x; f[4*c+1] = w.y; f[4*c+2] = w.z; f[4*c+3] = w.w;
            }
            float p[8];
            #pragma unroll
            for (int j = 0; j < 8; ++j) {
                const float t0 = f[j + 1]  + f[j + 25];
                const float t1 = f[j + 4]  + f[j + 22];
                const float t2 = f[j + 7]  + f[j + 19];
                const float t3 = f[j + 10] + f[j + 16];
                p[j] = fmaf(U0, t0, fmaf(U1, t1, fmaf(U2, t2,
                           fmaf(U3, t3, U4 * f[j + 13]))));
            }
            float* pr = P + v * PW + 8 * t;
            *(float4*)pr       = make_float4(p[0], p[1], p[2], p[3]);
            *(float4*)(pr + 4) = make_float4(p[4], p[5], p[6], p[7]);
        }
        __syncthreads();
    } else {
        // ---- B1: x -> blur tile with per-stage double-reflect (G^2 fused) ----
        // blur row br <-> blurred image row reflect101(row0-4+br); cols are the
        // double-reflected halo col0-4..col0+35 (40 px = 120 floats).
        for (int e = tid; e < 720; e += 256) {   // 24 rows x 30 quads
            const int br = e / 30;
            const int qc = e - br * 30;
            const int gg = row0 - 4 + br;
            const int gr = reflect101(gg, HIMG);
            const int ym = reflect101(gr - 1, HIMG);
            const int yp = reflect101(gr + 1, HIMG);
            // col safety for the vectorized window (needs identity cols lcp-1..lcp+1)
            const int lcpmin = (4 * qc) / 3;
            const int lcpmax = (4 * qc + 3) / 3;
            const bool safe = (col0 - 5 + lcpmin >= 0) && (col0 - 3 + lcpmax <= WIMG - 1);
            float4 r;
            if (safe) {
                const int fb = 3 * col0 - 16 + 4 * qc;   // 16B aligned
                const float* r0 = xi + (size_t)ym * ROWF + fb;
                const float* r1 = xi + (size_t)gr * ROWF + fb;
                const float* r2 = xi + (size_t)yp * ROWF + fb;
                float4 h[3];
                #pragma unroll
                for (int rr = 0; rr < 3; ++rr) {
                    const float* rp = (rr == 0) ? r0 : (rr == 1) ? r1 : r2;
                    const float4 a = *(const float4*)(rp);
                    const float4 b = *(const float4*)(rp + 4);
                    const float4 c = *(const float4*)(rp + 8);
                    h[rr] = make_float4(G0 * (a.y + b.w) + G1 * b.x,
                                        G0 * (a.z + c.x) + G1 * b.y,
                                        G0 * (a.w + c.y) + G1 * b.z,
                                        G0 * (b.x + c.z) + G1 * b.w);
                }
                r = g3(h[0], h[1], h[2], G0, G1);
            } else {
                float o[4];
                #pragma unroll
                for (int m = 0; m < 4; ++m) {
                    const int lc  = 4 * qc + m;
                    const int lcp = lc / 3;
                    const int ch  = lc - 3 * lcp;
                    const int gc  = reflect101(col0 - 4 + lcp, WIMG);
                    const int xm  = reflect101(gc - 1, WIMG) * 3 + ch;
                    const int x0  = gc * 3 + ch;
                    const int xp2 = reflect101(gc + 1, WIMG) * 3 + ch;
                    const float* r0 = xi + (size_t)ym * ROWF;
                    const float* r1 = xi + (size_t)gr * ROWF;
                    const float* r2 = xi + (size_t)yp * ROWF;
                    const float h0 = G0 * (r0[xm] + r0[xp2]) + G1 * r0[x0];
                    const float h1 = G0 * (r1[xm] + r1[xp2]) + G1 * r1[x0];
                    const float h2 = G0 * (r2[xm] + r2[xp2]) + G1 * r2[x0];
                    o[m] = G0 * (h0 + h2) + G1 * h1;
                }
                r = make_float4(o[0], o[1], o[2], o[3]);
            }
            *(float4*)&blur[br * BLW + 4 * qc] = r;
        }
        __syncthreads();

        // ---- B2: vertical 7-tap C6, blur -> vq (2-row register block) ----
        for (int g = tid; g < 270; g += 256) {   // 9 pairs x 30 quads
            const int lp = g / 30;
            const int qc = g - lp * 30;
            const float* bp = blur + (2 * lp) * BLW + 4 * qc;
            float4 w[8];
            #pragma unroll
            for (int k = 0; k < 8; ++k)
                w[k] = *(const float4*)(bp + k * BLW);
            float* vp = vq + (2 * lp) * VQW + 4 * qc;
            *(float4*)vp         = c6dot4(w[0], w[1], w[2], w[3], w[4], w[5], w[6]);
            *(float4*)(vp + VQW) = c6dot4(w[1], w[2], w[3], w[4], w[5], w[6], w[7]);
        }
        __syncthreads();   // blur dead beyond this point (P overlays it)

        // ---- B3: horizontal 7-tap C6, vq -> P ----
        // P[r][ps] = sum_k C6[k]*vq[r][ps+3k] (center vq float ps+9 <-> P float ps
        // <-> image float 3*col0-3+ps, consistent with S3').
        if (tid < 234) {                        // 18 rows x 13 groups of 8
            const int t = tid % 13;
            const int r = tid / 13;
            const float* v = vq + r * VQW + 8 * t;
            float f[28];
            #pragma unroll
            for (int c = 0; c < 7; ++c) {
                const float4 w = *(const float4*)(v + 4 * c);
                f[4*c+0] = w.x; f[4*c+1] = w.y; f[4*c+2] = w.z; f[4*c+3] = w.w;
            }
            float p[8];
            #pragma unroll
            for (int j = 0; j < 8; ++j)
                p[j] = c6dot(f[j], f[j+3], f[j+6], f[j+9], f[j+12], f[j+15], f[j+18]);
            float* pr = P + r * PW + 8 * t;
            *(float4*)pr       = make_float4(p[0], p[1], p[2], p[3]);
            *(float4*)(pr + 4) = make_float4(p[4], p[5], p[6], p[7]);
        }
        __syncthreads();
    }

    // ---- S3' (shared): 5-point cross on P, +1, clip, store ----
    // out[i][c] = 2*(P[i][c]+P[i][c+6]+P[i+2][c]+P[i+2][c+6]) - 8*P[i+1][c+3] + 1
    float* const outn = out + (size_t)n * HIMG * ROWF;
    for (int g = tid; g < TH * 12; g += 256) {
        const int i  = g / 12;
        const int qp = g - i * 12;
        const int o  = qp * 8;
        const float* pt = P + i * PW + o;
        const float* pm = pt + PW;
        const float* pb = pm + PW;
        float t[16], m[16], b[16];
        #pragma unroll
        for (int q = 0; q < 4; ++q) {
            const float4 vt = *(const float4*)(pt + 4 * q);
            t[4*q+0] = vt.x; t[4*q+1] = vt.y; t[4*q+2] = vt.z; t[4*q+3] = vt.w;
            const float4 vm = *(const float4*)(pm + 4 * q);
            m[4*q+0] = vm.x; m[4*q+1] = vm.y; m[4*q+2] = vm.z; m[4*q+3] = vm.w;
            const float4 vb = *(const float4*)(pb + 4 * q);
            b[4*q+0] = vb.x; b[4*q+1] = vb.y; b[4*q+2] = vb.z; b[4*q+3] = vb.w;
        }
        float o8[8];
        #pragma unroll
        for (int j = 0; j < 8; ++j) {
            const float c = m[j + 3];
            const float s = (t[j] - c) + (t[j + 6] - c) + (b[j] - c) + (b[j + 6] - c);
            const float v = fmaf(2.f, s, 1.f);
            o8[j] = fminf(fmaxf(v, 0.f), 255.f);
        }
        float* op = outn + (size_t)(row0 + i) * ROWF + (size_t)(col0 * 3 + o);
        *(float4*)op       = make_float4(o8[0], o8[1], o8[2], o8[3]);
        *(float4*)(op + 4) = make_float4(o8[4], o8[5], o8[6], o8[7]);
    }
}

extern "C" void kernel_launch(void* const* d_in, const int* in_sizes, int n_in,
                              void* d_out, int out_size, void* d_ws, size_t ws_size,
                              hipStream_t stream) {
    const float* x = (const float*)d_in[0];
    float* outp = (float*)d_out;
    const int nimg = in_sizes[0] / (HIMG * WIMG * 3);
    dim3 grid(WIMG / TW, HIMG / TH, nimg);
    log_fused<<<grid, dim3(256, 1, 1), 0, stream>>>(x, outp);
}

// Round 5
// 325.521 us; speedup vs baseline: 1.0045x; 1.0045x over previous
//
#include <hip/hip_runtime.h>

// LoG: GaussianBlur(3x3, sigma=1, BORDER_REFLECT_101) -> Laplacian(ksize=9) -> +1 -> clip[0,255]
// x: [32,512,512,3] float32 NHWC. out: same.
//
// Full composition: blur kernel G3xG3, lap kernel = (C6xC6) *2D cross3 where
//   S9 = C6*[1,2,1], D9 = C6*[1,-2,1], cross3 = [[2,0,2],[0,-8,0],[2,0,2]].
// With U = G3*C6 (9-tap, sum 64): total = (U x U) *2D cross3.
// INTERIOR blocks (out rows & cols in [5,506]; no reflect fires in the reference):
//   S1': x (global, registers) -vert 9-tap U-> vU (LDS)
//   S2': vU -horz 9-tap U-> P (LDS)
//   S3': 5-point cross on P -> +1, clip, store          [2 barriers, no x staging]
// BOUNDARY blocks (row/col tile 0 or last): per-stage reflect-101 preserved:
//   B1: x -> blur tile (G^2 fused on the fly, double-reflected rows/cols)
//   B2: blur -C6 vert-> vq;  B3: vq -C6 horz-> P;  shared S3'.
//
// R3/R4 lessons baked in:
//  * launch_bounds(256,4): caps VGPR at 128. (256,8)->VGPR64 and (256,6)->VGPR85
//    both forced scratch spills of the S2'/S3' register arrays (VGPR=32 reported,
//    dur 326us). Real usage ~64-84 -> occupancy lands at 5-7 blocks/CU anyway.
//  * ALL LDS words touched by vector loads are initialized: S1' writes full
//    33-quad rows (real data), S2' reads exactly f[34], B2 zero-fills vq pads,
//    S3' loads trimmed t[14]/m[12]/b[14]. R4's post-timing nondeterminism
//    (absmax 255 on replay) is attributed to uninitialized-LDS pad reads.

#define TH 16
#define TW 32
#define HIMG 512
#define WIMG 512
#define ROWF (WIMG*3)    // 1536 floats per image row

#define VUW 132          // vU stride (floats); 33 quads, ALL written (odd quad stride)
#define PW  108          // P stride; 104 written (34 px + pad)
#define BLW 120          // boundary blur stride (40 px)
#define VQW 124          // boundary vq stride (30 quads data + 1 zeroed pad quad)

// LDS float layout (aliased by path/stage):
//   interior: vU [0,2376)                     P [2376,4320)
//   boundary: vq [0,2232)  blur [2232,5112)   P [2376,4320) (overlays dead blur)
#define OFF_P  2376
#define OFF_BL 2232
#define SM_TOTAL 5112    // 20448 B

__device__ __forceinline__ int reflect101(int i, int n) {
    i = (i < 0) ? -i : i;
    return (i >= n) ? (2 * n - 2 - i) : i;
}

__device__ __forceinline__ float4 fma4(float s, const float4& a, const float4& b) {
    return make_float4(fmaf(s, a.x, b.x), fmaf(s, a.y, b.y),
                       fmaf(s, a.z, b.z), fmaf(s, a.w, b.w));
}

__device__ __forceinline__ float c6dot(float f0, float f1, float f2, float f3,
                                       float f4, float f5, float f6) {
    return fmaf(20.f, f3, fmaf(6.f, f1 + f5, fmaf(15.f, f2 + f4, f0 + f6)));
}

__device__ __forceinline__ float4 c6dot4(const float4& a, const float4& b, const float4& c,
                                         const float4& d, const float4& e, const float4& f,
                                         const float4& g) {
    return make_float4(c6dot(a.x, b.x, c.x, d.x, e.x, f.x, g.x),
                       c6dot(a.y, b.y, c.y, d.y, e.y, f.y, g.y),
                       c6dot(a.z, b.z, c.z, d.z, e.z, f.z, g.z),
                       c6dot(a.w, b.w, c.w, d.w, e.w, f.w, g.w));
}

__device__ __forceinline__ float4 g3(const float4& a, const float4& b, const float4& c,
                                     float G0, float G1) {
    return make_float4(G0 * (a.x + c.x) + G1 * b.x,
                       G0 * (a.y + c.y) + G1 * b.y,
                       G0 * (a.z + c.z) + G1 * b.z,
                       G0 * (a.w + c.w) + G1 * b.w);
}

// U = G3 * C6: {U0,U1,U2,U3,U4,U3,U2,U1,U0}, sum = 64
#define U0 0.27406862f
#define U1 2.09627447f
#define U2 7.09627447f
#define U3 13.90372553f
#define U4 17.25931382f

__global__ __launch_bounds__(256, 4)
void log_fused(const float* __restrict__ x, float* __restrict__ out) {
    __shared__ __align__(16) float smem[SM_TOTAL];
    float* const vU   = smem;            // interior: 18 x 132
    float* const vq   = smem;            // boundary: 18 x 124
    float* const blur = smem + OFF_BL;   // boundary: 24 x 120
    float* const P    = smem + OFF_P;    // both:     18 x 108

    const int tid  = threadIdx.x;
    const int col0 = blockIdx.x * TW;
    const int row0 = blockIdx.y * TH;
    const int n    = blockIdx.z;
    const float* const xi = x + (size_t)n * HIMG * ROWF;

    const float G0 = 0.2740686190f, G1 = 0.4518627620f;

    const bool interior = (row0 != 0) && (row0 != HIMG - TH) &&
                          (col0 != 0) && (col0 != WIMG - TW);

    if (interior) {
        // ---- S1': vertical 9-tap U, x(global) -> vU, 2-row register block ----
        // vU row v (0..17) <-> image row row0-1+v; vU float f <-> x float 3*col0-16+f.
        // 33 quads/row: the pad quad (floats 128..131) gets REAL data so S2's
        // vector reads never see uninitialized LDS. x cols stay in-bounds
        // (max float 3*448+115 = 1459 < 1536 for interior col0 <= 448).
        const float Uk[10] = {U0, U1, U2, U3, U4, U3, U2, U1, U0, 0.f};
        for (int g = tid; g < 297; g += 256) {   // 9 row-pairs x 33 quads
            const int q  = g % 33;
            const int rp = g / 33;               // 0..8
            const float* xp = xi + (size_t)(row0 - 5 + 2 * rp) * ROWF
                                 + (3 * col0 - 16 + 4 * q);
            float4 a0 = make_float4(0.f, 0.f, 0.f, 0.f), a1 = a0;
            #pragma unroll
            for (int j = 0; j < 10; ++j) {
                const float4 w = *(const float4*)(xp + (size_t)j * ROWF);
                if (j < 9) a0 = fma4(Uk[j], w, a0);
                if (j > 0) a1 = fma4(Uk[j - 1], w, a1);
            }
            float* vp = vU + (2 * rp) * VUW + 4 * q;
            *(float4*)vp         = a0;
            *(float4*)(vp + VUW) = a1;
        }
        __syncthreads();

        // ---- S2': horizontal 9-tap U (pixel stride = 3 floats), vU -> P ----
        // P float j <-> image float 3*col0-3+j; P[j] = sum_k U[k]*vU[j+1+3k].
        // Window trimmed to exactly f[34] (max consumed index f[33]).
        if (tid < 234) {                        // 18 rows x 13 groups of 8
            const int t = tid % 13;
            const int v = tid / 13;
            const float* vr = vU + v * VUW + 8 * t;
            float f[34];
            #pragma unroll
            for (int c = 0; c < 8; ++c) {
                const float4 w = *(const float4*)(vr + 4 * c);
                f[4*c+0] = w.x; f[4*c+1] = w.y; f[4*c+2] = w.z; f[4*c+3] = w.w;
            }
            const float2 w2 = *(const float2*)(vr + 32);
            f[32] = w2.x; f[33] = w2.y;
            float p[8];
            #pragma unroll
            for (int j = 0; j < 8; ++j) {
                const float t0 = f[j + 1]  + f[j + 25];
                const float t1 = f[j + 4]  + f[j + 22];
                const float t2 = f[j + 7]  + f[j + 19];
                const float t3 = f[j + 10] + f[j + 16];
                p[j] = fmaf(U0, t0, fmaf(U1, t1, fmaf(U2, t2,
                           fmaf(U3, t3, U4 * f[j + 13]))));
            }
            float* pr = P + v * PW + 8 * t;
            *(float4*)pr       = make_float4(p[0], p[1], p[2], p[3]);
            *(float4*)(pr + 4) = make_float4(p[4], p[5], p[6], p[7]);
        }
        __syncthreads();
    } else {
        // Zero vq pad quads up front so B3's vector reads never touch
        // uninitialized LDS (vq region is untouched by B1).
        if (tid < 18)
            *(float4*)&vq[tid * VQW + 120] = make_float4(0.f, 0.f, 0.f, 0.f);

        // ---- B1: x -> blur tile with per-stage double-reflect (G^2 fused) ----
        for (int e = tid; e < 720; e += 256) {   // 24 rows x 30 quads
            const int br = e / 30;
            const int qc = e - br * 30;
            const int gg = row0 - 4 + br;
            const int gr = reflect101(gg, HIMG);
            const int ym = reflect101(gr - 1, HIMG);
            const int yp = reflect101(gr + 1, HIMG);
            const int lcpmin = (4 * qc) / 3;
            const int lcpmax = (4 * qc + 3) / 3;
            const bool safe = (col0 - 5 + lcpmin >= 0) && (col0 - 3 + lcpmax <= WIMG - 1);
            float4 r;
            if (safe) {
                const int fb = 3 * col0 - 16 + 4 * qc;   // 16B aligned
                const float* r0 = xi + (size_t)ym * ROWF + fb;
                const float* r1 = xi + (size_t)gr * ROWF + fb;
                const float* r2 = xi + (size_t)yp * ROWF + fb;
                float4 h[3];
                #pragma unroll
                for (int rr = 0; rr < 3; ++rr) {
                    const float* rp = (rr == 0) ? r0 : (rr == 1) ? r1 : r2;
                    const float4 a = *(const float4*)(rp);
                    const float4 b = *(const float4*)(rp + 4);
                    const float4 c = *(const float4*)(rp + 8);
                    h[rr] = make_float4(G0 * (a.y + b.w) + G1 * b.x,
                                        G0 * (a.z + c.x) + G1 * b.y,
                                        G0 * (a.w + c.y) + G1 * b.z,
                                        G0 * (b.x + c.z) + G1 * b.w);
                }
                r = g3(h[0], h[1], h[2], G0, G1);
            } else {
                float o[4];
                #pragma unroll
                for (int m = 0; m < 4; ++m) {
                    const int lc  = 4 * qc + m;
                    const int lcp = lc / 3;
                    const int ch  = lc - 3 * lcp;
                    const int gc  = reflect101(col0 - 4 + lcp, WIMG);
                    const int xm  = reflect101(gc - 1, WIMG) * 3 + ch;
                    const int x0  = gc * 3 + ch;
                    const int xp2 = reflect101(gc + 1, WIMG) * 3 + ch;
                    const float* r0 = xi + (size_t)ym * ROWF;
                    const float* r1 = xi + (size_t)gr * ROWF;
                    const float* r2 = xi + (size_t)yp * ROWF;
                    const float h0 = G0 * (r0[xm] + r0[xp2]) + G1 * r0[x0];
                    const float h1 = G0 * (r1[xm] + r1[xp2]) + G1 * r1[x0];
                    const float h2 = G0 * (r2[xm] + r2[xp2]) + G1 * r2[x0];
                    o[m] = G0 * (h0 + h2) + G1 * h1;
                }
                r = make_float4(o[0], o[1], o[2], o[3]);
            }
            *(float4*)&blur[br * BLW + 4 * qc] = r;
        }
        __syncthreads();

        // ---- B2: vertical 7-tap C6, blur -> vq (2-row register block) ----
        for (int g = tid; g < 270; g += 256) {   // 9 pairs x 30 quads
            const int lp = g / 30;
            const int qc = g - lp * 30;
            const float* bp = blur + (2 * lp) * BLW + 4 * qc;
            float4 w[8];
            #pragma unroll
            for (int k = 0; k < 8; ++k)
                w[k] = *(const float4*)(bp + k * BLW);
            float* vp = vq + (2 * lp) * VQW + 4 * qc;
            *(float4*)vp         = c6dot4(w[0], w[1], w[2], w[3], w[4], w[5], w[6]);
            *(float4*)(vp + VQW) = c6dot4(w[1], w[2], w[3], w[4], w[5], w[6], w[7]);
        }
        __syncthreads();   // blur dead beyond this point (P overlays it)

        // ---- B3: horizontal 7-tap C6, vq -> P ----
        if (tid < 234) {                        // 18 rows x 13 groups of 8
            const int t = tid % 13;
            const int r = tid / 13;
            const float* v = vq + r * VQW + 8 * t;
            float f[28];
            #pragma unroll
            for (int c = 0; c < 7; ++c) {
                const float4 w = *(const float4*)(v + 4 * c);
                f[4*c+0] = w.x; f[4*c+1] = w.y; f[4*c+2] = w.z; f[4*c+3] = w.w;
            }
            float p[8];
            #pragma unroll
            for (int j = 0; j < 8; ++j)
                p[j] = c6dot(f[j], f[j+3], f[j+6], f[j+9], f[j+12], f[j+15], f[j+18]);
            float* pr = P + r * PW + 8 * t;
            *(float4*)pr       = make_float4(p[0], p[1], p[2], p[3]);
            *(float4*)(pr + 4) = make_float4(p[4], p[5], p[6], p[7]);
        }
        __syncthreads();
    }

    // ---- S3' (shared): 5-point cross on P, +1, clip, store ----
    // out[i][c] = 2*(P[i][c]+P[i][c+6]+P[i+2][c]+P[i+2][c+6]) - 8*P[i+1][c+3] + 1
    // Loads trimmed to the consumed window: t[0..13], m[0..11], b[0..13].
    float* const outn = out + (size_t)n * HIMG * ROWF;
    for (int g = tid; g < TH * 12; g += 256) {
        const int i  = g / 12;
        const int qp = g - i * 12;
        const int o  = qp * 8;
        const float* pt = P + i * PW + o;
        const float* pm = pt + PW;
        const float* pb = pm + PW;
        float t[14], m[12], b[14];
        #pragma unroll
        for (int q = 0; q < 3; ++q) {
            const float4 vt = *(const float4*)(pt + 4 * q);
            t[4*q+0] = vt.x; t[4*q+1] = vt.y; t[4*q+2] = vt.z; t[4*q+3] = vt.w;
            const float4 vb = *(const float4*)(pb + 4 * q);
            b[4*q+0] = vb.x; b[4*q+1] = vb.y; b[4*q+2] = vb.z; b[4*q+3] = vb.w;
            const float4 vm = *(const float4*)(pm + 4 * q);
            m[4*q+0] = vm.x; m[4*q+1] = vm.y; m[4*q+2] = vm.z; m[4*q+3] = vm.w;
        }
        const float2 t2 = *(const float2*)(pt + 12);
        t[12] = t2.x; t[13] = t2.y;
        const float2 b2 = *(const float2*)(pb + 12);
        b[12] = b2.x; b[13] = b2.y;
        float o8[8];
        #pragma unroll
        for (int j = 0; j < 8; ++j) {
            const float c = m[j + 3];
            const float s = (t[j] - c) + (t[j + 6] - c) + (b[j] - c) + (b[j + 6] - c);
            const float v = fmaf(2.f, s, 1.f);
            o8[j] = fminf(fmaxf(v, 0.f), 255.f);
        }
        float* op = outn + (size_t)(row0 + i) * ROWF + (size_t)(col0 * 3 + o);
        *(float4*)op       = make_float4(o8[0], o8[1], o8[2], o8[3]);
        *(float4*)(op + 4) = make_float4(o8[4], o8[5], o8[6], o8[7]);
    }
}

extern "C" void kernel_launch(void* const* d_in, const int* in_sizes, int n_in,
                              void* d_out, int out_size, void* d_ws, size_t ws_size,
                              hipStream_t stream) {
    const float* x = (const float*)d_in[0];
    float* outp = (float*)d_out;
    const int nimg = in_sizes[0] / (HIMG * WIMG * 3);
    dim3 grid(WIMG / TW, HIMG / TH, nimg);
    log_fused<<<grid, dim3(256, 1, 1), 0, stream>>>(x, outp);
}

// Round 6
// 228.180 us; speedup vs baseline: 1.4331x; 1.4266x over previous
//
#include <hip/hip_runtime.h>

// LoG: GaussianBlur(3x3, sigma=1, BORDER_REFLECT_101) -> Laplacian(ksize=9) -> +1 -> clip[0,255]
// x: [32,512,512,3] float32 NHWC. out: same.
//
// Factorization: S9 = C6*[1,2,1], D9 = C6*[1,-2,1], C6 = {1,6,15,20,15,6,1}
//   lap = outer(S9,D9)+outer(D9,S9) = (C6 (x) C6) o [[2,0,2],[0,-8,0],[2,0,2]]
// Stages: s1 horiz G3 (global->hblur), s2 vert G3 (hblur->blur),
//   3a vert C6 (blur->vq), 3b horz C6 (vq->P), 3c 5-pt cross (P->out).
// This is the R2 structure (verified 107us/dispatch, VGPR=40, no spills).
// R3-R5's composed-from-global variant is abandoned: it codegen'd to VGPR=32
// latency-chain code (211us) regardless of launch_bounds.
//
// R6 changes vs R2 (bank conflicts only):
//  * 3b/3c rewritten from 8-outputs/lane (32B lane stride -> even bank-quads
//    only, 2-4x serialization; the ~1.9e7 conflict floor across R1/R2/R5) to
//    4-outputs/lane with CONSECUTIVE-lane->CONSECUTIVE-quad ownership: every
//    f4 read is a rotated coalesced pattern (lane i -> quad (i+c) mod 8),
//    conflict-free by construction.
//  * vq pad quad zeroed (replay-determinism; R4 lesson: no LDS read may touch
//    uninitialized words).

#define TH 16
#define TW 32
#define FW (TW*3)        // 96 output floats per tile row
#define BF ((TW+8)*3)    // 120 floats per hblur/blur row (+-4 px halo)
#define BH (TH+8)        // 24 blur rows
#define PH (TH+2)        // 18 vq/P rows (out rows -1..16)
#define VW 124           // vq row stride (31 quads: 30 data + 1 zeroed pad)
#define PW 108           // P row stride (27 quads; 26 written)
#define HIMG 512
#define WIMG 512
#define ROWF (WIMG*3)    // 1536 floats per image row

// LDS floats: A [0,3120): hblur(<=26x120) -> vq(18x124=2232)
//             B [3120,6000): blur(24x120=2880) -> P(18x108=1944)
#define OFF_B 3120
#define SM_TOTAL 6000    // 24000 B -> 6 blocks/CU

__device__ __forceinline__ int reflect101(int i, int n) {
    i = (i < 0) ? -i : i;
    return (i >= n) ? (2 * n - 2 - i) : i;
}

__device__ __forceinline__ float c6dot(float f0, float f1, float f2, float f3,
                                       float f4, float f5, float f6) {
    // {1,6,15,20,15,6,1} symmetric: 3 adds + 3 fma
    return fmaf(20.f, f3, fmaf(6.f, f1 + f5, fmaf(15.f, f2 + f4, f0 + f6)));
}

__device__ __forceinline__ float4 c6dot4(const float4& a, const float4& b, const float4& c,
                                         const float4& d, const float4& e, const float4& f,
                                         const float4& g) {
    return make_float4(c6dot(a.x, b.x, c.x, d.x, e.x, f.x, g.x),
                       c6dot(a.y, b.y, c.y, d.y, e.y, f.y, g.y),
                       c6dot(a.z, b.z, c.z, d.z, e.z, f.z, g.z),
                       c6dot(a.w, b.w, c.w, d.w, e.w, f.w, g.w));
}

__device__ __forceinline__ float4 g3(const float4& a, const float4& b, const float4& c,
                                     float G0, float G1) {
    return make_float4(G0 * (a.x + c.x) + G1 * b.x,
                       G0 * (a.y + c.y) + G1 * b.y,
                       G0 * (a.z + c.z) + G1 * b.z,
                       G0 * (a.w + c.w) + G1 * b.w);
}

__global__ __launch_bounds__(256, 6)
void log_fused(const float* __restrict__ x, float* __restrict__ out) {
    __shared__ __align__(16) float smem[SM_TOTAL];
    float* const hblur = smem;           // 26 x 120
    float* const vq    = smem;           // 18 x 124 (aliases hblur, after it's dead)
    float* const blur  = smem + OFF_B;   // 24 x 120
    float* const P     = smem + OFF_B;   // 18 x 108 (aliases blur, after it's dead)

    const int tid  = threadIdx.x;
    const int col0 = blockIdx.x * TW;
    const int row0 = blockIdx.y * TH;
    const int n    = blockIdx.z;

    const int R0    = max(0, row0 - 5);
    const int R1    = min(HIMG - 1, row0 + TH + 4);
    const int nrows = R1 - R0 + 1;   // <= 26

    const float G0 = 0.2740686190f, G1 = 0.4518627620f;  // normalized exp(-{1,0,1}/2)

    // ---- stage 1: horizontal 3-tap Gaussian, global -> hblur ----
    const bool edgecol = (col0 == 0) || (col0 + TW == WIMG);
    if (!edgecol) {
        // Interior columns: vectorized. 3*col0 % 4 == 0 so the 12-float window
        // starting at x-float 3*(col0-4)+4*cg-4 is 16B aligned.
        if (tid < 240) {
            const int cg = tid % 30;
            const int rg = tid / 30;            // 0..7
            const float* xb = x + ((size_t)n * HIMG + (size_t)(R0 + rg)) * ROWF
                                + (3 * (col0 - 4) + 4 * cg - 4);
            float* hb = hblur + rg * BF + 4 * cg;
            for (int r = rg; r < nrows; r += 8, xb += 8 * ROWF, hb += 8 * BF) {
                const float4 a = *(const float4*)(xb);
                const float4 b = *(const float4*)(xb + 4);
                const float4 c = *(const float4*)(xb + 8);
                float4 o;
                o.x = G0 * (a.y + b.w) + G1 * b.x;
                o.y = G0 * (a.z + c.x) + G1 * b.y;
                o.z = G0 * (a.w + c.y) + G1 * b.z;
                o.w = G0 * (b.x + c.z) + G1 * b.w;
                *(float4*)hb = o;
            }
        }
    } else {
        // Edge-column blocks (2/16): scalar column-LUT path with double-reflect.
        if (tid < 240) {
            const int lc  = tid % BF;
            const int rg  = tid / BF;           // 0 or 1
            const int lcp = lc / 3;
            const int ch  = lc - 3 * lcp;
            const int gc  = reflect101(col0 - 4 + lcp, WIMG);
            const int xm  = reflect101(gc - 1, WIMG) * 3 + ch;
            const int x0  = gc * 3 + ch;
            const int xp  = reflect101(gc + 1, WIMG) * 3 + ch;
            const float* xr = x + ((size_t)n * HIMG + (size_t)(R0 + rg)) * ROWF;
            for (int r = rg; r < nrows; r += 2, xr += 2 * ROWF) {
                hblur[r * BF + lc] = G0 * (xr[xm] + xr[xp]) + G1 * xr[x0];
            }
        }
    }
    __syncthreads();

    // ---- stage 2: vertical 3-tap Gaussian, hblur -> blur (2-row pairs) ----
    if (row0 > 0 && row0 + TH < HIMG) {
        for (int g = tid; g < 12 * 30; g += 256) {
            const int lp = g / 30;
            const int qc = g - lp * 30;
            const float* hb = hblur + (2 * lp) * BF + qc * 4;
            const float4 w0 = *(const float4*)(hb);
            const float4 w1 = *(const float4*)(hb + BF);
            const float4 w2 = *(const float4*)(hb + 2 * BF);
            const float4 w3 = *(const float4*)(hb + 3 * BF);
            float* bp = blur + (2 * lp) * BF + qc * 4;
            *(float4*)bp        = g3(w0, w1, w2, G0, G1);
            *(float4*)(bp + BF) = g3(w1, w2, w3, G0, G1);
        }
    } else {
        // Boundary tiles: full double-reflect per pair row.
        for (int g = tid; g < 12 * 30; g += 256) {
            const int lp = g / 30;
            const int qc = g - lp * 30;
            const int gg = row0 - 4 + 2 * lp;
            const int y0 = reflect101(gg, HIMG);
            const int y1 = reflect101(gg + 1, HIMG);
            const int lc = qc * 4;
            const float4 a0 = *(const float4*)&hblur[(reflect101(y0 - 1, HIMG) - R0) * BF + lc];
            const float4 a1 = *(const float4*)&hblur[(y0 - R0) * BF + lc];
            const float4 a2 = *(const float4*)&hblur[(reflect101(y0 + 1, HIMG) - R0) * BF + lc];
            const float4 b0 = *(const float4*)&hblur[(reflect101(y1 - 1, HIMG) - R0) * BF + lc];
            const float4 b1 = *(const float4*)&hblur[(y1 - R0) * BF + lc];
            const float4 b2 = *(const float4*)&hblur[(reflect101(y1 + 1, HIMG) - R0) * BF + lc];
            float* bp = blur + (2 * lp) * BF + lc;
            *(float4*)bp        = g3(a0, a1, a2, G0, G1);
            *(float4*)(bp + BF) = g3(b0, b1, b2, G0, G1);
        }
    }
    __syncthreads();   // hblur dead beyond this point (vq overlays it)

    // Zero the vq pad quad (floats 120..123 per row): 3b's q=25 window reads
    // floats up to 121; their products only reach unconsumed P[102..103], but
    // no LDS read may touch uninitialized words (replay-determinism, R4).
    if (tid < PH)
        *(float4*)&vq[tid * VW + 120] = make_float4(0.f, 0.f, 0.f, 0.f);

    // ---- stage 3a: vertical 7-tap C6, blur -> vq (2-row register block) ----
    for (int g = tid; g < 9 * 30; g += 256) {
        const int lp = g / 30;
        const int qc = g - lp * 30;
        const float* bp = blur + (2 * lp) * BF + qc * 4;
        float4 w[8];
        #pragma unroll
        for (int k = 0; k < 8; ++k)
            w[k] = *(const float4*)(bp + k * BF);
        float* vp = vq + (2 * lp) * VW + qc * 4;
        *(float4*)vp        = c6dot4(w[0], w[1], w[2], w[3], w[4], w[5], w[6]);
        *(float4*)(vp + VW) = c6dot4(w[1], w[2], w[3], w[4], w[5], w[6], w[7]);
    }
    __syncthreads();   // blur dead beyond this point (P overwrites it)

    // ---- stage 3b: horizontal 7-tap C6, vq -> P (4 outputs/lane) ----
    // P[r][ps] = sum_k C6[k]*vq[r][ps+3k]. Group (r, q): P quad q (floats
    // 4q..4q+3), window vq floats 4q..4q+21 -> 6 consecutive f4 reads.
    // Consecutive lanes own consecutive quads -> conflict-free reads/writes.
    for (int g = tid; g < PH * 26; g += 256) {   // 468 groups
        const int r = g / 26;
        const int q = g - r * 26;
        const float* v = vq + r * VW + 4 * q;
        float f[24];
        #pragma unroll
        for (int c = 0; c < 6; ++c) {
            const float4 w = *(const float4*)(v + 4 * c);
            f[4*c+0] = w.x; f[4*c+1] = w.y; f[4*c+2] = w.z; f[4*c+3] = w.w;
        }
        float p[4];
        #pragma unroll
        for (int j = 0; j < 4; ++j)
            p[j] = c6dot(f[j], f[j+3], f[j+6], f[j+9], f[j+12], f[j+15], f[j+18]);
        *(float4*)&P[r * PW + 4 * q] = make_float4(p[0], p[1], p[2], p[3]);
    }
    __syncthreads();

    // ---- stage 3c: 5-point cross on P, +1, clip, store (4 outputs/lane) ----
    // out[i][c] = 2*(P[i][c]+P[i][c+6]+P[i+2][c]+P[i+2][c+6]) - 8*P[i+1][c+3] + 1
    // Group (i, q): out floats 4q..4q+3; reads 3 consecutive f4 per P row
    // (floats 4q..4q+11 cover both c..c+9 and middle c+3..c+9).
    float* const outn = out + (size_t)n * HIMG * ROWF;
    for (int g = tid; g < TH * 24; g += 256) {   // 384 groups
        const int i = g / 24;
        const int q = g - i * 24;
        const float* pt = P + i * PW + 4 * q;
        const float* pm = pt + PW;
        const float* pb = pm + PW;
        float t[12], m[12], b[12];
        #pragma unroll
        for (int c = 0; c < 3; ++c) {
            const float4 vt = *(const float4*)(pt + 4 * c);
            t[4*c+0] = vt.x; t[4*c+1] = vt.y; t[4*c+2] = vt.z; t[4*c+3] = vt.w;
            const float4 vm = *(const float4*)(pm + 4 * c);
            m[4*c+0] = vm.x; m[4*c+1] = vm.y; m[4*c+2] = vm.z; m[4*c+3] = vm.w;
            const float4 vb = *(const float4*)(pb + 4 * c);
            b[4*c+0] = vb.x; b[4*c+1] = vb.y; b[4*c+2] = vb.z; b[4*c+3] = vb.w;
        }
        float o4[4];
        #pragma unroll
        for (int j = 0; j < 4; ++j) {
            const float c = m[j + 3];
            const float s = (t[j] - c) + (t[j + 6] - c) + (b[j] - c) + (b[j + 6] - c);
            const float v = fmaf(2.f, s, 1.f);
            o4[j] = fminf(fmaxf(v, 0.f), 255.f);
        }
        float* op = outn + (size_t)(row0 + i) * ROWF + (size_t)(col0 * 3 + 4 * q);
        *(float4*)op = make_float4(o4[0], o4[1], o4[2], o4[3]);
    }
}

extern "C" void kernel_launch(void* const* d_in, const int* in_sizes, int n_in,
                              void* d_out, int out_size, void* d_ws, size_t ws_size,
                              hipStream_t stream) {
    const float* x = (const float*)d_in[0];
    float* outp = (float*)d_out;
    const int nimg = in_sizes[0] / (HIMG * WIMG * 3);
    dim3 grid(WIMG / TW, HIMG / TH, nimg);
    log_fused<<<grid, dim3(256, 1, 1), 0, stream>>>(x, outp);
}

// Round 8
// 221.677 us; speedup vs baseline: 1.4751x; 1.0293x over previous
//
#include <hip/hip_runtime.h>

// LoG: GaussianBlur(3x3, sigma=1, BORDER_REFLECT_101) -> Laplacian(ksize=9) -> +1 -> clip[0,255]
// x: [32,512,512,3] float32 NHWC. out: same.
//
// Factorization: S9 = C6*[1,2,1], D9 = C6*[1,-2,1], C6 = {1,6,15,20,15,6,1}
//   lap = outer(S9,D9)+outer(D9,S9) = (C6 (x) C6) o [[2,0,2],[0,-8,0],[2,0,2]]
// R7 pipeline (3 barriers):
//   s1: horiz G3, global -> hblur                     (R2's proven stage)
//   fv: VERTICAL 9-tap U9 = G3v * C6v, hblur -> vq    (fuses R2's s2+3a;
//       -2340 f4 LDS ops, -1 barrier; identical FMA count since 9-tap
//       costs 9 ops/px = G3's 3 + C6's 6)
//   3b: horiz C6, vq -> P  (8-out/lane, R2 form; R6's 4-out was worse)
//   3c: 5-pt cross on P -> +1, clip, store (8-out/lane, trimmed middle row)
// Boundary ROW tiles use an exact double-reflect fused path in fv
// (7x [3-tap G3 + C6 accumulate]); boundary COL tiles handled in s1 as before.
//
// Conflict-model note (R0-R6 data): SQ_LDS_BANK_CONFLICT ~ 6-8 cyc per wave64
// ds_read_b128 REGARDLESS of addressing (intrinsic 256-dword/32-bank
// serialization). Only fewer LDS instructions help -> this round cuts f4 LDS
// thread-ops 10050 -> ~7540 and LDS 24.0 KB -> 20.9 KB (6 -> 7 blocks/CU).

#define TH 16
#define TW 32
#define BF ((TW+8)*3)    // 120 floats per hblur row (+-4 px halo)
#define PH (TH+2)        // 18 vq/P rows (out rows -1..16)
#define VW 124           // vq row stride (31 quads: 30 data + 1 zeroed pad)
#define PW 108           // P row stride (27 quads; 26 written)
#define HIMG 512
#define WIMG 512
#define ROWF (WIMG*3)    // 1536 floats per image row

// LDS floats: hblur [0,3120) (26x120); vq [3120,5352) (18x124);
//             P [0,1944) aliases hblur (dead after fv).
#define OFF_VQ 3120
#define SM_TOTAL 5352    // 21408 B -> 7 blocks/CU

__device__ __forceinline__ int reflect101(int i, int n) {
    i = (i < 0) ? -i : i;
    return (i >= n) ? (2 * n - 2 - i) : i;
}

__device__ __forceinline__ float4 fma4(float s, const float4& a, const float4& b) {
    return make_float4(fmaf(s, a.x, b.x), fmaf(s, a.y, b.y),
                       fmaf(s, a.z, b.z), fmaf(s, a.w, b.w));
}

__device__ __forceinline__ float c6dot(float f0, float f1, float f2, float f3,
                                       float f4, float f5, float f6) {
    return fmaf(20.f, f3, fmaf(6.f, f1 + f5, fmaf(15.f, f2 + f4, f0 + f6)));
}

__device__ __forceinline__ float4 g3(const float4& a, const float4& b, const float4& c,
                                     float G0, float G1) {
    return make_float4(G0 * (a.x + c.x) + G1 * b.x,
                       G0 * (a.y + c.y) + G1 * b.y,
                       G0 * (a.z + c.z) + G1 * b.z,
                       G0 * (a.w + c.w) + G1 * b.w);
}

// U9 = conv(G3, C6), symmetric 9-tap, sum 64
#define U0 0.27406862f
#define U1 2.09627447f
#define U2 7.09627447f
#define U3 13.90372553f
#define U4 17.25931382f

__global__ __launch_bounds__(256, 6)
void log_fused(const float* __restrict__ x, float* __restrict__ out) {
    __shared__ __align__(16) float smem[SM_TOTAL];
    float* const hblur = smem;            // 26 x 120
    float* const P     = smem;            // 18 x 108 (aliases hblur after fv)
    float* const vq    = smem + OFF_VQ;   // 18 x 124

    const int tid  = threadIdx.x;
    const int col0 = blockIdx.x * TW;
    const int row0 = blockIdx.y * TH;
    const int n    = blockIdx.z;

    const int R0    = max(0, row0 - 5);
    const int R1    = min(HIMG - 1, row0 + TH + 4);
    const int nrows = R1 - R0 + 1;   // 26 interior, 21 at row boundaries

    const float G0 = 0.2740686190f, G1 = 0.4518627620f;  // normalized exp(-{1,0,1}/2)

    // Zero vq pad quads (floats 120..123 per row): 3b's qp=12 window reads
    // floats up to 123; no LDS read may touch uninitialized words (R4 lesson).
    // vq region is disjoint from hblur, so this needs no extra barrier.
    if (tid < PH)
        *(float4*)&vq[tid * VW + 120] = make_float4(0.f, 0.f, 0.f, 0.f);

    // ---- s1: horizontal 3-tap Gaussian, global -> hblur (R2 verbatim) ----
    const bool edgecol = (col0 == 0) || (col0 + TW == WIMG);
    if (!edgecol) {
        // Interior columns: vectorized. 3*col0 % 4 == 0 so the 12-float window
        // starting at x-float 3*(col0-4)+4*cg-4 is 16B aligned.
        if (tid < 240) {
            const int cg = tid % 30;
            const int rg = tid / 30;            // 0..7
            const float* xb = x + ((size_t)n * HIMG + (size_t)(R0 + rg)) * ROWF
                                + (3 * (col0 - 4) + 4 * cg - 4);
            float* hb = hblur + rg * BF + 4 * cg;
            for (int r = rg; r < nrows; r += 8, xb += 8 * ROWF, hb += 8 * BF) {
                const float4 a = *(const float4*)(xb);
                const float4 b = *(const float4*)(xb + 4);
                const float4 c = *(const float4*)(xb + 8);
                float4 o;
                o.x = G0 * (a.y + b.w) + G1 * b.x;
                o.y = G0 * (a.z + c.x) + G1 * b.y;
                o.z = G0 * (a.w + c.y) + G1 * b.z;
                o.w = G0 * (b.x + c.z) + G1 * b.w;
                *(float4*)hb = o;
            }
        }
    } else {
        // Edge-column blocks (2/16): scalar column-LUT path with double-reflect.
        if (tid < 240) {
            const int lc  = tid % BF;
            const int rg  = tid / BF;           // 0 or 1
            const int lcp = lc / 3;
            const int ch  = lc - 3 * lcp;
            const int gc  = reflect101(col0 - 4 + lcp, WIMG);
            const int xm  = reflect101(gc - 1, WIMG) * 3 + ch;
            const int x0  = gc * 3 + ch;
            const int xp  = reflect101(gc + 1, WIMG) * 3 + ch;
            const float* xr = x + ((size_t)n * HIMG + (size_t)(R0 + rg)) * ROWF;
            for (int r = rg; r < nrows; r += 2, xr += 2 * ROWF) {
                hblur[r * BF + lc] = G0 * (xr[xm] + xr[xp]) + G1 * xr[x0];
            }
        }
    }
    __syncthreads();

    // ---- fv: fused vertical 9-tap (G3v * C6v), hblur -> vq ----
    // Interior row-tiles: vq[r] = sum_j U9[j] * hblurT[r+j]  (rows 0..25, no
    // reflect fires: hblurT row h <-> image row row0-5+h, all in [0,511]).
    if (row0 != 0 && row0 != HIMG - TH) {
        if (tid < 180) {                       // 6 row-triples x 30 quads
            const int rg = tid / 30;           // 0..5
            const int qc = tid % 30;
            const float U9k[9] = {U0, U1, U2, U3, U4, U3, U2, U1, U0};
            const float* hb = hblur + (3 * rg) * BF + 4 * qc;
            float4 a0 = make_float4(0.f, 0.f, 0.f, 0.f), a1 = a0, a2 = a0;
            #pragma unroll
            for (int j = 0; j < 11; ++j) {
                const float4 w = *(const float4*)(hb + j * BF);
                if (j <= 8)           a0 = fma4(U9k[j],     w, a0);
                if (j >= 1 && j <= 9) a1 = fma4(U9k[j - 1], w, a1);
                if (j >= 2)           a2 = fma4(U9k[j - 2], w, a2);
            }
            float* vp = vq + (3 * rg) * VW + 4 * qc;
            *(float4*)vp            = a0;
            *(float4*)(vp + VW)     = a1;
            *(float4*)(vp + 2 * VW) = a2;
        }
    } else {
        // Boundary row-tiles (2/32): exact per-stage reflect.
        // vq[r] = sum_k C6[k] * blur_img[reflect(row0-4+r+k)],
        // blur_img[y] = G0*(hbI[refl(y-1)] + hbI[refl(y+1)]) + G1*hbI[y],
        // hbI row y staged at hblur[y - R0]  (all y land in [R0,R1]).
        const float C6k[7] = {1.f, 6.f, 15.f, 20.f, 15.f, 6.f, 1.f};
        for (int g = tid; g < PH * 30; g += 256) {   // 540 groups
            const int r  = g / 30;
            const int qc = g - r * 30;
            const int gb = row0 - 4 + r;
            float4 acc = make_float4(0.f, 0.f, 0.f, 0.f);
            #pragma unroll
            for (int k = 0; k < 7; ++k) {
                const int y  = reflect101(gb + k, HIMG);
                const int ym = reflect101(y - 1, HIMG) - R0;
                const int yp = reflect101(y + 1, HIMG) - R0;
                const float4 a = *(const float4*)&hblur[ym * BF + 4 * qc];
                const float4 b = *(const float4*)&hblur[(y - R0) * BF + 4 * qc];
                const float4 c = *(const float4*)&hblur[yp * BF + 4 * qc];
                acc = fma4(C6k[k], g3(a, b, c, G0, G1), acc);
            }
            *(float4*)&vq[r * VW + 4 * qc] = acc;
        }
    }
    __syncthreads();   // hblur dead beyond this point (P overlays it)

    // ---- 3b: horizontal 7-tap C6, vq -> P (8 outputs/lane, R2 form) ----
    // P[r][ps] = sum_k C6[k]*vq[r][ps+3k]; window floats 8qp..8qp+27 (7 f4
    // reads; last read touches the zeroed pad at qp=12).
    if (tid < PH * 13) {                        // 234 groups
        const int qp = tid % 13;
        const int r  = tid / 13;
        const float* v = vq + r * VW + 8 * qp;
        float f[28];
        #pragma unroll
        for (int c = 0; c < 7; ++c) {
            const float4 w = *(const float4*)(v + 4 * c);
            f[4*c+0] = w.x; f[4*c+1] = w.y; f[4*c+2] = w.z; f[4*c+3] = w.w;
        }
        float p[8];
        #pragma unroll
        for (int j = 0; j < 8; ++j)
            p[j] = c6dot(f[j], f[j+3], f[j+6], f[j+9], f[j+12], f[j+15], f[j+18]);
        float* pr = P + r * PW + 8 * qp;
        *(float4*)pr       = make_float4(p[0], p[1], p[2], p[3]);
        *(float4*)(pr + 4) = make_float4(p[4], p[5], p[6], p[7]);
    }
    __syncthreads();

    // ---- 3c: 5-point cross on P, +1, clip, store (8 outputs/lane) ----
    // out[i][c] = 2*(P[i][c]+P[i][c+6]+P[i+2][c]+P[i+2][c+6]) - 8*P[i+1][c+3] + 1
    // Reads: top 4 f4, middle 3 f4 (m[3..10] consumed), bottom 4 f4.
    float* const outn = out + (size_t)n * HIMG * ROWF;
    if (tid < TH * 12) {                        // 192 groups
        const int qp = tid % 12;
        const int i  = tid / 12;
        const int o  = qp * 8;
        const float* pt = P + i * PW + o;
        const float* pm = pt + PW;
        const float* pb = pm + PW;
        float t[16], m[12], b[16];
        #pragma unroll
        for (int q = 0; q < 4; ++q) {
            const float4 vt = *(const float4*)(pt + 4 * q);
            t[4*q+0] = vt.x; t[4*q+1] = vt.y; t[4*q+2] = vt.z; t[4*q+3] = vt.w;
            const float4 vb = *(const float4*)(pb + 4 * q);
            b[4*q+0] = vb.x; b[4*q+1] = vb.y; b[4*q+2] = vb.z; b[4*q+3] = vb.w;
        }
        #pragma unroll
        for (int q = 0; q < 3; ++q) {
            const float4 vm = *(const float4*)(pm + 4 * q);
            m[4*q+0] = vm.x; m[4*q+1] = vm.y; m[4*q+2] = vm.z; m[4*q+3] = vm.w;
        }
        float o8[8];
        #pragma unroll
        for (int j = 0; j < 8; ++j) {
            const float c = m[j + 3];
            const float s = (t[j] - c) + (t[j + 6] - c) + (b[j] - c) + (b[j + 6] - c);
            const float v = fmaf(2.f, s, 1.f);
            o8[j] = fminf(fmaxf(v, 0.f), 255.f);
        }
        float* op = outn + (size_t)(row0 + i) * ROWF + (size_t)(col0 * 3 + o);
        *(float4*)op       = make_float4(o8[0], o8[1], o8[2], o8[3]);
        *(float4*)(op + 4) = make_float4(o8[4], o8[5], o8[6], o8[7]);
    }
}

extern "C" void kernel_launch(void* const* d_in, const int* in_sizes, int n_in,
                              void* d_out, int out_size, void* d_ws, size_t ws_size,
                              hipStream_t stream) {
    const float* x = (const float*)d_in[0];
    float* outp = (float*)d_out;
    const int nimg = in_sizes[0] / (HIMG * WIMG * 3);
    dim3 grid(WIMG / TW, HIMG / TH, nimg);
    log_fused<<<grid, dim3(256, 1, 1), 0, stream>>>(x, outp);
}